// Round 19
// baseline (1865.357 us; speedup 1.0000x reference)
//
#include <hip/hip_runtime.h>

// ODE-GRU on MI355X, round 19 — MFMA rewrite.
// 32 blocks x 512 threads (8 waves); block owns 16 batch rows, full SEQ=256
// recurrence in-block. All matvecs become 16xNxK GEMMs on the matrix pipe
// via mfma_f32_16x16x32_f16 (MfmaUtil was 0.0 for 18 rounds of VALU-dot2).
// Weights pre-laid as B-fragments (prep kernel) -> coalesced h8 loads,
// L2-resident (557 KB). A-frags from padded LDS. C/D layout = HW-verified
// (col=lane&15, row=(lane>>4)*4+reg). h state f32 in LDS master.
// Integrator: forward Euler (validated r16/r17/r18, absmax invariant).
// 3 barriers/step. Fallback if absmax fails: r16 (1200 us).

#define SEQ   256
#define BATCH 512
#define DIN   54
#define HDIM  256
#define DH    64
#define ROWS  16

typedef _Float16 h8 __attribute__((ext_vector_type(8)));
typedef float f32x4 __attribute__((ext_vector_type(4)));

#define MFMA16(A, B, C) __builtin_amdgcn_mfma_f32_16x16x32_f16((A), (B), (C), 0, 0, 0)

__device__ __forceinline__ float rcp_f(float x) { return __builtin_amdgcn_rcpf(x); }

__device__ __forceinline__ float fast_tanh(float x) {
    x = fminf(15.0f, fmaxf(-15.0f, x));
    float e = __expf(2.0f * x);
    return 1.0f - 2.0f * rcp_f(e + 1.0f);
}
__device__ __forceinline__ float fast_sigmoid(float x) {
    x = fminf(30.0f, fmaxf(-30.0f, x));
    return rcp_f(1.0f + __expf(-x));
}

// ---- prep: weights -> B-fragment layout, f16 ----
// Tile (nt, kt), lane l holds W[nt*16 + (l&15)][kt*32 + (l>>4)*8 .. +7] (h8).
// WHHF: 48 nt x 8 kt (Whh 768x256)      -> 24576 h8
// WIHF: 48 nt x 2 kt (Wih 768x54, pad)  ->  6144 h8
// W1F :  4 nt x 8 kt (W1   64x256)      ->  2048 h8
// W2F : 16 nt x 2 kt (W2  256x64)       ->  2048 h8
__global__ __launch_bounds__(256)
void prep_kernel(const float* __restrict__ W_ih, const float* __restrict__ W_hh,
                 const float* __restrict__ W1,  const float* __restrict__ W2,
                 h8* __restrict__ WHHF, h8* __restrict__ WIHF,
                 h8* __restrict__ W1F,  h8* __restrict__ W2F)
{
    const int id = blockIdx.x * 256 + threadIdx.x;
    h8 v;
    if (id < 24576) {
        const int nt = id >> 9, kt = (id >> 6) & 7, l = id & 63;
        const float* src = W_hh + (size_t)(nt * 16 + (l & 15)) * HDIM
                         + kt * 32 + (l >> 4) * 8;
        #pragma unroll
        for (int e = 0; e < 8; ++e) v[e] = (_Float16)src[e];
        WHHF[id] = v;
    } else if (id < 30720) {
        const int id2 = id - 24576;
        const int nt = id2 >> 7, kt = (id2 >> 6) & 1, l = id2 & 63;
        const int row = nt * 16 + (l & 15);
        const int k0  = kt * 32 + (l >> 4) * 8;
        #pragma unroll
        for (int e = 0; e < 8; ++e) {
            const int col = k0 + e;
            v[e] = (col < DIN) ? (_Float16)W_ih[(size_t)row * DIN + col]
                               : (_Float16)0.0f;
        }
        WIHF[id2] = v;
    } else if (id < 32768) {
        const int id3 = id - 30720;
        const int a1 = id3 >> 9, kt = (id3 >> 6) & 7, l = id3 & 63;
        const float* src = W1 + (size_t)(a1 * 16 + (l & 15)) * HDIM
                         + kt * 32 + (l >> 4) * 8;
        #pragma unroll
        for (int e = 0; e < 8; ++e) v[e] = (_Float16)src[e];
        W1F[id3] = v;
    } else if (id < 34816) {
        const int id4 = id - 32768;
        const int a2 = id4 >> 7, kt = (id4 >> 6) & 1, l = id4 & 63;
        const float* src = W2 + (size_t)(a2 * 16 + (l & 15)) * DH
                         + kt * 32 + (l >> 4) * 8;
        #pragma unroll
        for (int e = 0; e < 8; ++e) v[e] = (_Float16)src[e];
        W2F[id4] = v;
    }
}

// Wave w (0..7) owns j-tiles {w, w+8} for GRU gates and drift stage2;
// waves 0..3 own stage1 tile a1=w. Per step per wave: 60 GRU mfma +
// 8 stage1 (w<4) + 4 stage2. D-frag element (reg rr): m = (l>>4)*4+rr
// (batch row), n = tile*16 + (l&15) (output index) -- HW-verified layout.
__global__ void
__attribute__((amdgpu_flat_work_group_size(512, 512), amdgpu_waves_per_eu(2, 2)))
odegru_kernel(const float* __restrict__ x,
              const float* __restrict__ tvec,
              const float* __restrict__ b_ih,
              const float* __restrict__ b_hh,
              const float* __restrict__ b1,
              const float* __restrict__ b2,
              const h8* __restrict__ WHHF, const h8* __restrict__ WIHF,
              const h8* __restrict__ W1F,  const h8* __restrict__ W2F,
              float* __restrict__ out)
{
    const int t  = threadIdx.x;
    const int w  = t >> 6;          // wave 0..7
    const int l  = t & 63;
    const int lm = l & 15, lg = l >> 4;
    const int brow0 = blockIdx.x * ROWS;

    // +8 f16 row pad -> A-frag ds_read_b128 spreads uniformly over banks.
    __shared__ __align__(16) _Float16 H16[16][264];   // h (f16 mirror, A-op)
    __shared__ __align__(16) _Float16 Y16[16][264];   // h_gru (drift A-op)
    __shared__ __align__(16) _Float16 U16[16][72];    // tanh(W1 y) (A-op)
    __shared__ __align__(16) _Float16 XH [16][72];    // x step tile (A-op)
    __shared__ float HF32[16][257];                   // h master (f32)
    __shared__ float dts[SEQ];

    for (int k2 = t; k2 < 16 * 264; k2 += 512) (&H16[0][0])[k2] = (_Float16)0.0f;
    for (int k2 = t; k2 < 16 * 257; k2 += 512) (&HF32[0][0])[k2] = 0.0f;
    if (t < SEQ) dts[t] = (t > 0) ? (tvec[t - 1] - tvec[t]) : 0.0f;

    float brzr[2], brzz[2], binx[2], bhnx[2], b2s[2];
    #pragma unroll
    for (int aa = 0; aa < 2; ++aa) {
        const int jj = (w + aa * 8) * 16 + lm;
        brzr[aa] = b_ih[jj]       + b_hh[jj];
        brzz[aa] = b_ih[jj + 256] + b_hh[jj + 256];
        binx[aa] = b_ih[jj + 512];
        bhnx[aa] = b_hh[jj + 512];
        b2s[aa]  = b2[jj];
    }
    const float b1s = (w < 4) ? b1[w * 16 + lm] : 0.0f;

    for (int i = 0; i < SEQ; ++i) {
        const int s = SEQ - 1 - i;

        #pragma unroll
        for (int rep = 0; rep < 2; ++rep) {
            const int idx = t + rep * 512;
            const int row = idx >> 6, col = idx & 63;
            XH[row][col] = (col < DIN)
                ? (_Float16)x[((size_t)s * BATCH + brow0 + row) * DIN + col]
                : (_Float16)0.0f;
        }
        __syncthreads();                               // B1

        // ---- GRU GEMM: D[m][j-tile] over K=256 (H) + K=64 (X) ----
        f32x4 accr[2]  = {};
        f32x4 accz[2]  = {};
        f32x4 accnh[2] = {};
        f32x4 accnx[2] = {};
        #pragma unroll
        for (int kt = 0; kt < 8; ++kt) {
            h8 Af = *(const h8*)&H16[lm][kt * 32 + lg * 8];
            #pragma unroll
            for (int aa = 0; aa < 2; ++aa) {
                const int a = w + aa * 8;
                accr[aa]  = MFMA16(Af, WHHF[((     a) * 8 + kt) * 64 + l], accr[aa]);
                accz[aa]  = MFMA16(Af, WHHF[((16 + a) * 8 + kt) * 64 + l], accz[aa]);
                accnh[aa] = MFMA16(Af, WHHF[((32 + a) * 8 + kt) * 64 + l], accnh[aa]);
            }
        }
        #pragma unroll
        for (int kt = 0; kt < 2; ++kt) {
            h8 Xf = *(const h8*)&XH[lm][kt * 32 + lg * 8];
            #pragma unroll
            for (int aa = 0; aa < 2; ++aa) {
                const int a = w + aa * 8;
                accr[aa]  = MFMA16(Xf, WIHF[((     a) * 2 + kt) * 64 + l], accr[aa]);
                accz[aa]  = MFMA16(Xf, WIHF[((16 + a) * 2 + kt) * 64 + l], accz[aa]);
                accnx[aa] = MFMA16(Xf, WIHF[((32 + a) * 2 + kt) * 64 + l], accnx[aa]);
            }
        }

        // ---- gates (elementwise on D-frags; h_old from f32 master) ----
        float hn[2][4];
        #pragma unroll
        for (int aa = 0; aa < 2; ++aa) {
            const int jj = (w + aa * 8) * 16 + lm;
            #pragma unroll
            for (int rr = 0; rr < 4; ++rr) {
                const int m = lg * 4 + rr;
                const float hold = HF32[m][jj];
                const float rg = fast_sigmoid(accr[aa][rr] + brzr[aa]);
                const float zg = fast_sigmoid(accz[aa][rr] + brzz[aa]);
                const float ng = fast_tanh(accnx[aa][rr] + binx[aa]
                                          + rg * (accnh[aa][rr] + bhnx[aa]));
                hn[aa][rr] = ng + zg * (hold - ng);
            }
        }

        // ---- drift: forward Euler over [t0, t1] ----
        const float dt = dts[s];
        if (dt != 0.0f) {   // block-uniform (dt==0 only at s==0, final iter)
            #pragma unroll
            for (int aa = 0; aa < 2; ++aa) {
                const int jj = (w + aa * 8) * 16 + lm;
                #pragma unroll
                for (int rr = 0; rr < 4; ++rr)
                    Y16[lg * 4 + rr][jj] = (_Float16)hn[aa][rr];
            }
            __syncthreads();                           // B2
            if (w < 4) {                               // stage1: U = tanh(Y W1^T + b1)
                f32x4 au = {};
                #pragma unroll
                for (int kt = 0; kt < 8; ++kt) {
                    h8 Yf = *(const h8*)&Y16[lm][kt * 32 + lg * 8];
                    au = MFMA16(Yf, W1F[(w * 8 + kt) * 64 + l], au);
                }
                #pragma unroll
                for (int rr = 0; rr < 4; ++rr)
                    U16[lg * 4 + rr][w * 16 + lm] = (_Float16)fast_tanh(au[rr] + b1s);
            }
            __syncthreads();                           // B3
            #pragma unroll
            for (int aa = 0; aa < 2; ++aa) {           // stage2: k = U W2^T + b2
                f32x4 ak = {};
                #pragma unroll
                for (int kt = 0; kt < 2; ++kt) {
                    h8 Uf = *(const h8*)&U16[lm][kt * 32 + lg * 8];
                    ak = MFMA16(Uf, W2F[((w + aa * 8) * 2 + kt) * 64 + l], ak);
                }
                const int jj = (w + aa * 8) * 16 + lm;
                #pragma unroll
                for (int rr = 0; rr < 4; ++rr) {
                    const int m = lg * 4 + rr;
                    const float hf = fmaf(dt, ak[rr] + b2s[aa], hn[aa][rr]);
                    HF32[m][jj] = hf;
                    H16[m][jj]  = (_Float16)hf;
                    __builtin_nontemporal_store(hf,
                        &out[((size_t)s * BATCH + brow0 + m) * HDIM + jj]);
                }
            }
        } else {
            __syncthreads();   // drain H16/HF32 readers before overwrite
            #pragma unroll
            for (int aa = 0; aa < 2; ++aa) {
                const int jj = (w + aa * 8) * 16 + lm;
                #pragma unroll
                for (int rr = 0; rr < 4; ++rr) {
                    const int m = lg * 4 + rr;
                    HF32[m][jj] = hn[aa][rr];
                    H16[m][jj]  = (_Float16)hn[aa][rr];
                    __builtin_nontemporal_store(hn[aa][rr],
                        &out[((size_t)s * BATCH + brow0 + m) * HDIM + jj]);
                }
            }
        }
        // WAR audit: XH write(pre-B1) vs reads(pre-B2): spans B2,B3.
        // H16/HF32 writes(post-B3) vs reads(post-B1 next): B1 orders RAW;
        // reads(this step) vs writes: spans B2,B3. Y16 write(pre-B2) vs
        // stage1 reads: B2; next write: spans B3,B1. U16 write(B2..B3) vs
        // reads(post-B3): B3; next write: spans B1,B2.
    }
}

extern "C" void kernel_launch(void* const* d_in, const int* in_sizes, int n_in,
                              void* d_out, int out_size, void* d_ws, size_t ws_size,
                              hipStream_t stream) {
    const float* x    = (const float*)d_in[0];
    const float* tvec = (const float*)d_in[1];
    const float* W_ih = (const float*)d_in[2];
    const float* W_hh = (const float*)d_in[3];
    const float* b_ih = (const float*)d_in[4];
    const float* b_hh = (const float*)d_in[5];
    const float* W1   = (const float*)d_in[6];
    const float* b1   = (const float*)d_in[7];
    const float* W2   = (const float*)d_in[8];
    const float* b2   = (const float*)d_in[9];
    float* out = (float*)d_out;

    h8* WHHF = (h8*)d_ws;                               // 393216 B
    h8* WIHF = (h8*)((char*)d_ws + 393216);             //  98304 B
    h8* W1F  = (h8*)((char*)d_ws + 491520);             //  32768 B
    h8* W2F  = (h8*)((char*)d_ws + 524288);             //  32768 B (total 557056)

    hipLaunchKernelGGL(prep_kernel, dim3(136), dim3(256), 0, stream,
                       W_ih, W_hh, W1, W2, WHHF, WIHF, W1F, W2F);
    hipLaunchKernelGGL(odegru_kernel, dim3(BATCH / ROWS), dim3(512), 0, stream,
                       x, tvec, b_ih, b_hh, b1, b2, WHHF, WIHF, W1F, W2F, out);
}

// Round 20
// 1666.208 us; speedup vs baseline: 1.1195x; 1.1195x over previous
//
#include <hip/hip_runtime.h>

// ODE-GRU on MI355X, round 20.
// Chassis = round 16 (256 blocks x 512 thr, dual-row register-amortized f16
// dot2, DPP reductions, forward Euler, 3 barriers/step, nontemporal out).
// Change: GRU weight stream staged via __builtin_amdgcn_global_load_lds —
// async DMA to LDS, ZERO VGPR cost (the register-prefetch failure mode of
// r8/r11/r15 cannot occur). Weights re-laid by prep as a sequential stream
// WS[u=0..59][t]; per wave, 10 chunks x 6 units into a 3-deep LDS ring
// (wave-private regions -> no barriers; same-wave issue/consume ordering
// makes ring reuse race-free). Counted s_waitcnt vmcnt(12/6/0) keeps 2
// chunks in flight (depth-2 pipeline). VALU work + accumulation order
// bitwise-identical to r16 -> absmax must be EXACTLY 0.00390625.
// r19 lesson: MFMA caps at 32 blocks (M=16 tiling) = 108K FLOP/cyc chip-wide
// < VALU's 131K on 256 CUs -> MFMA structurally inferior for this op.

#define SEQ   256
#define BATCH 512
#define DIN   54
#define HDIM  256
#define DH    64

typedef _Float16 h2 __attribute__((ext_vector_type(2)));
typedef _Float16 h8 __attribute__((ext_vector_type(8)));

#define PX(v, p) __builtin_shufflevector((v), (v), 2*(p), 2*(p)+1)

#if defined(__has_builtin)
#  if __has_builtin(__builtin_amdgcn_fdot2)
#    define FDOT2(a, b, c) __builtin_amdgcn_fdot2((a), (b), (c), false)
#  endif
#  if __has_builtin(__builtin_amdgcn_global_load_lds)
#    define HAVE_GLL 1
#  endif
#endif
#ifndef FDOT2
#  define FDOT2(a, b, c) fmaf((float)(a)[0], (float)(b)[0], \
                         fmaf((float)(a)[1], (float)(b)[1], (c)))
#endif

#define AS1 __attribute__((address_space(1)))
#define AS3 __attribute__((address_space(3)))

__device__ __forceinline__ float rcp_f(float x) { return __builtin_amdgcn_rcpf(x); }

__device__ __forceinline__ float fast_tanh(float x) {
    x = fminf(15.0f, fmaxf(-15.0f, x));
    float e = __expf(2.0f * x);
    return 1.0f - 2.0f * rcp_f(e + 1.0f);
}
__device__ __forceinline__ float fast_sigmoid(float x) {
    x = fminf(30.0f, fmaxf(-30.0f, x));
    return rcp_f(1.0f + __expf(-x));
}

template <int CTRL>
__device__ __forceinline__ float dppadd(float x) {
    return x + __int_as_float(
        __builtin_amdgcn_mov_dpp(__float_as_int(x), CTRL, 0xF, 0xF, true));
}

#define DOT8(A, W, Y) { \
    A = FDOT2(PX(W,0), PX(Y,0), A); A = FDOT2(PX(W,1), PX(Y,1), A); \
    A = FDOT2(PX(W,2), PX(Y,2), A); A = FDOT2(PX(W,3), PX(Y,3), A); }

// ---- prep: GRU weights as sequential consumption stream WS[u][t] ----
// u = 3q+g        (q=0..3,  g=r/z/n): W_ih[(t>>1)+256g][(t&1)*32+q*8 ..+8]
//                  (cols >= 54 zero-padded)
// u = 12+3q+g     (q=0..15, g=r/z/n): W_hh[(t>>1)+256g][(t&1)*128+q*8 ..+8]
__global__ __launch_bounds__(256)
void prep_kernel(const float* __restrict__ W_ih, const float* __restrict__ W_hh,
                 h8* __restrict__ WS)
{
    const int id = blockIdx.x * 256 + threadIdx.x;
    if (id >= 60 * 512) return;
    const int u = id >> 9, t = id & 511;
    const int j = t >> 1, p = t & 1;
    h8 v;
    if (u < 12) {
        const int q = u / 3, g = u % 3;
        #pragma unroll
        for (int e = 0; e < 8; ++e) {
            const int col = p * 32 + q * 8 + e;
            v[e] = (col < DIN) ? (_Float16)W_ih[(size_t)(j + 256 * g) * DIN + col]
                               : (_Float16)0.0f;
        }
    } else {
        const int u2 = u - 12;
        const int q = u2 / 3, g = u2 % 3;
        const float* src = W_hh + (size_t)(j + 256 * g) * HDIM + p * 128 + q * 8;
        #pragma unroll
        for (int e = 0; e < 8; ++e) v[e] = (_Float16)src[e];
    }
    WS[id] = v;
}

#ifdef HAVE_GLL
// Stage chunk c (6 units) into ring buffer c%3; wave-private LDS region.
#define ISSUE_CHUNK(c) { \
    _Pragma("unroll") \
    for (int uc_ = 0; uc_ < 6; ++uc_) { \
        __builtin_amdgcn_global_load_lds( \
            (const AS1 void*)(WS + (size_t)((c) * 6 + uc_) * 512 + t), \
            (AS3 void*)(&WSL[(((c) % 3) * 6 + uc_) * 512 + (w << 6)]), \
            16, 0, 0); \
    } }
#define WAITV12 asm volatile("s_waitcnt vmcnt(12)" ::: "memory")
#define WAITV6  asm volatile("s_waitcnt vmcnt(6)"  ::: "memory")
#define WAITV0  asm volatile("s_waitcnt vmcnt(0)"  ::: "memory")
#define WUNIT(c, uc) WSL[(((c) % 3) * 6 + (uc)) * 512 + t]
#else
#define ISSUE_CHUNK(c)
#define WAITV12
#define WAITV6
#define WAITV0
#define WUNIT(c, uc) WS[(size_t)((c) * 6 + (uc)) * 512 + t]
#endif

#define USE_IH(c, uc, q, A0, A1) { \
    h8 wv_ = WUNIT(c, uc); \
    h8 x0_ = *(const h8*)(xh0 + p * 32 + (q) * 8); \
    h8 x1_ = *(const h8*)(xh1 + p * 32 + (q) * 8); \
    DOT8(A0, wv_, x0_) DOT8(A1, wv_, x1_) }

#define USE_HH(c, uc, q, A0, A1) { \
    h8 wv_ = WUNIT(c, uc); \
    h8 y0_ = *(const h8*)(yG0 + p * 128 + (q) * 8); \
    h8 y1_ = *(const h8*)(yG1 + p * 128 + (q) * 8); \
    DOT8(A0, wv_, y0_) DOT8(A1, wv_, y1_) }

// One hh chunk = 2 q-groups x 3 gates.
#define HH_CHUNK(c, q0) \
    USE_HH(c, 0, (q0),     hr0, hr1) USE_HH(c, 1, (q0),     hz0, hz1) \
    USE_HH(c, 2, (q0),     hn0, hn1) USE_HH(c, 3, (q0) + 1, hr0, hr1) \
    USE_HH(c, 4, (q0) + 1, hz0, hz1) USE_HH(c, 5, (q0) + 1, hn0, hn1)

__global__ void
__attribute__((amdgpu_flat_work_group_size(512, 512), amdgpu_waves_per_eu(2, 2)))
odegru_kernel(const float* __restrict__ x,
              const float* __restrict__ tvec,
              const float* __restrict__ b_ih,
              const float* __restrict__ b_hh,
              const float* __restrict__ W1,
              const float* __restrict__ b1,
              const float* __restrict__ W2,
              const float* __restrict__ b2,
              const h8* __restrict__ WS,
              float* __restrict__ out)
{
    const int t  = threadIdx.x;          // 0..511
    const int w  = t >> 6;               // wave 0..7
    const int b0 = blockIdx.x * 2;       // batch row A
    const int bB = b0 + 1;               // batch row B
    const int j  = t >> 1;               // element 0..255
    const int p  = t & 1;                // pair half
    const int i1 = t >> 3;               // drift stage1 output 0..63
    const int k8 = t & 7;                // stage1 k-chunk

    __shared__ __align__(16) _Float16 yG0[HDIM], yG1[HDIM];
    __shared__ __align__(16) _Float16 yh0[HDIM], yh1[HDIM];
    __shared__ __align__(16) _Float16 uh0[DH],  uh1[DH];
    __shared__ __align__(16) _Float16 xh0[64],  xh1[64];
#ifdef HAVE_GLL
    __shared__ __align__(16) h8 WSL[3 * 6 * 512];   // 144 KB ring, wave-private
#endif
    __shared__ float dts[SEQ];

    if (t < SEQ) dts[t] = (t > 0) ? (tvec[t - 1] - tvec[t]) : 0.0f;

    // Drift weights -> 8 named h8 vars (32 VGPRs), shared by both rows.
    h8 w1m0, w1m1, w1m2, w1m3, w2q0, w2q1, w2q2, w2q3;
    {
        const float* base = W1 + (size_t)i1 * HDIM + k8 * 8;
        h8 v;
        #pragma unroll
        for (int e = 0; e < 8; ++e) v[e] = (_Float16)base[e +   0]; w1m0 = v;
        #pragma unroll
        for (int e = 0; e < 8; ++e) v[e] = (_Float16)base[e +  64]; w1m1 = v;
        #pragma unroll
        for (int e = 0; e < 8; ++e) v[e] = (_Float16)base[e + 128]; w1m2 = v;
        #pragma unroll
        for (int e = 0; e < 8; ++e) v[e] = (_Float16)base[e + 192]; w1m3 = v;
    }
    {
        const float* base = W2 + (size_t)j * DH + p * 32;
        h8 v;
        #pragma unroll
        for (int e = 0; e < 8; ++e) v[e] = (_Float16)base[e +  0]; w2q0 = v;
        #pragma unroll
        for (int e = 0; e < 8; ++e) v[e] = (_Float16)base[e +  8]; w2q1 = v;
        #pragma unroll
        for (int e = 0; e < 8; ++e) v[e] = (_Float16)base[e + 16]; w2q2 = v;
        #pragma unroll
        for (int e = 0; e < 8; ++e) v[e] = (_Float16)base[e + 24]; w2q3 = v;
    }

    const float b1r  = b1[i1];
    const float b2r  = b2[j];
    const float bihr = b_ih[j], bihz = b_ih[j + HDIM], bihn = b_ih[j + 2 * HDIM];
    const float bhhr = b_hh[j], bhhz = b_hh[j + HDIM], bhhn = b_hh[j + 2 * HDIM];

    float h0 = 0.0f, h1 = 0.0f;

    for (int i = 0; i < SEQ; ++i) {
        const int s = SEQ - 1 - i;

        // Prefetch first two chunks; their latency drains under B1.
        ISSUE_CHUNK(0); ISSUE_CHUNK(1);

        if (t < 64) {
            xh0[t] = (t < DIN) ? (_Float16)x[((size_t)s * BATCH + b0) * DIN + t]
                               : (_Float16)0.0f;
        } else if (t < 128) {
            const int u = t - 64;
            xh1[u] = (u < DIN) ? (_Float16)x[((size_t)s * BATCH + bB) * DIN + u]
                               : (_Float16)0.0f;
        }
        if (p == 0) { yG0[j] = (_Float16)h0; yG1[j] = (_Float16)h1; }
        __syncthreads();                                   // B1 (top)

        float xr0 = 0.f, xz0 = 0.f, xn0 = 0.f;
        float xr1 = 0.f, xz1 = 0.f, xn1 = 0.f;
        float hr0 = 0.f, hz0 = 0.f, hn0 = 0.f;
        float hr1 = 0.f, hz1 = 0.f, hn1 = 0.f;

        // ---- depth-2 pipelined chunk consumption (10 chunks) ----
        ISSUE_CHUNK(2); WAITV12;
        USE_IH(0, 0, 0, xr0, xr1) USE_IH(0, 1, 0, xz0, xz1) USE_IH(0, 2, 0, xn0, xn1)
        USE_IH(0, 3, 1, xr0, xr1) USE_IH(0, 4, 1, xz0, xz1) USE_IH(0, 5, 1, xn0, xn1)
        ISSUE_CHUNK(3); WAITV12;
        USE_IH(1, 0, 2, xr0, xr1) USE_IH(1, 1, 2, xz0, xz1) USE_IH(1, 2, 2, xn0, xn1)
        USE_IH(1, 3, 3, xr0, xr1) USE_IH(1, 4, 3, xz0, xz1) USE_IH(1, 5, 3, xn0, xn1)
        ISSUE_CHUNK(4); WAITV12; HH_CHUNK(2,  0)
        ISSUE_CHUNK(5); WAITV12; HH_CHUNK(3,  2)
        ISSUE_CHUNK(6); WAITV12; HH_CHUNK(4,  4)
        ISSUE_CHUNK(7); WAITV12; HH_CHUNK(5,  6)
        ISSUE_CHUNK(8); WAITV12; HH_CHUNK(6,  8)
        ISSUE_CHUNK(9); WAITV12; HH_CHUNK(7, 10)
        WAITV6;  HH_CHUNK(8, 12)
        WAITV0;  HH_CHUNK(9, 14)

        {
            float Rp = dppadd<0xB1>(xr0 + hr0);
            float Zp = dppadd<0xB1>(xz0 + hz0);
            float Ip = dppadd<0xB1>(xn0);
            float Hp = dppadd<0xB1>(hn0);
            float r_g = fast_sigmoid(Rp + bihr + bhhr);
            float z_g = fast_sigmoid(Zp + bihz + bhhz);
            float n_g = fast_tanh(Ip + bihn + r_g * (Hp + bhhn));
            h0 = n_g + z_g * (h0 - n_g);
        }
        {
            float Rp = dppadd<0xB1>(xr1 + hr1);
            float Zp = dppadd<0xB1>(xz1 + hz1);
            float Ip = dppadd<0xB1>(xn1);
            float Hp = dppadd<0xB1>(hn1);
            float r_g = fast_sigmoid(Rp + bihr + bhhr);
            float z_g = fast_sigmoid(Zp + bihz + bhhz);
            float n_g = fast_tanh(Ip + bihn + r_g * (Hp + bhhn));
            h1 = n_g + z_g * (h1 - n_g);
        }
        // no barrier: drift writes yh* (not yG*); yG* WAR gap spans B2+B3.

        // ---- ODE integrate: forward Euler (1 dual-row drift) ----
        const float dt = dts[s];

        if (dt != 0.0f) {   // block-uniform; dt==0 only at s==0 (exact skip)
            if (p == 0) { yh0[j] = (_Float16)h0; yh1[j] = (_Float16)h1; }
            __syncthreads();                               // B2
            float a00 = 0.f, a01 = 0.f, a10 = 0.f, a11 = 0.f;
            {
                h8 v;
                v = *(const h8*)(yh0 + k8 * 8 +   0); DOT8(a00, w1m0, v)
                v = *(const h8*)(yh0 + k8 * 8 +  64); DOT8(a01, w1m1, v)
                v = *(const h8*)(yh0 + k8 * 8 + 128); DOT8(a00, w1m2, v)
                v = *(const h8*)(yh0 + k8 * 8 + 192); DOT8(a01, w1m3, v)
                v = *(const h8*)(yh1 + k8 * 8 +   0); DOT8(a10, w1m0, v)
                v = *(const h8*)(yh1 + k8 * 8 +  64); DOT8(a11, w1m1, v)
                v = *(const h8*)(yh1 + k8 * 8 + 128); DOT8(a10, w1m2, v)
                v = *(const h8*)(yh1 + k8 * 8 + 192); DOT8(a11, w1m3, v)
            }
            float as0 = a00 + a01, as1 = a10 + a11;
            as0 = dppadd<0xB1>(as0);  as1 = dppadd<0xB1>(as1);
            as0 = dppadd<0x4E>(as0);  as1 = dppadd<0x4E>(as1);
            as0 = dppadd<0x141>(as0); as1 = dppadd<0x141>(as1);
            float uu0 = fast_tanh(as0 + b1r);
            float uu1 = fast_tanh(as1 + b1r);
            if (k8 == 0) { uh0[i1] = (_Float16)uu0; uh1[i1] = (_Float16)uu1; }
            __syncthreads();                               // B3
            float c00 = 0.f, c01 = 0.f, c10 = 0.f, c11 = 0.f;
            {
                h8 u;
                u = *(const h8*)(uh0 + p * 32 +  0); DOT8(c00, w2q0, u)
                u = *(const h8*)(uh0 + p * 32 +  8); DOT8(c01, w2q1, u)
                u = *(const h8*)(uh0 + p * 32 + 16); DOT8(c00, w2q2, u)
                u = *(const h8*)(uh0 + p * 32 + 24); DOT8(c01, w2q3, u)
                u = *(const h8*)(uh1 + p * 32 +  0); DOT8(c10, w2q0, u)
                u = *(const h8*)(uh1 + p * 32 +  8); DOT8(c11, w2q1, u)
                u = *(const h8*)(uh1 + p * 32 + 16); DOT8(c10, w2q2, u)
                u = *(const h8*)(uh1 + p * 32 + 24); DOT8(c11, w2q3, u)
            }
            float k0 = dppadd<0xB1>(c00 + c01) + b2r;
            float k1 = dppadd<0xB1>(c10 + c11) + b2r;
            h0 = fmaf(dt, k0, h0);
            h1 = fmaf(dt, k1, h1);
        } else {
            __syncthreads();   // degenerate dt: keep next-step writes ordered
        }

        if (p == 0) {
            __builtin_nontemporal_store(h0, &out[((size_t)s * BATCH + b0) * HDIM + j]);
            __builtin_nontemporal_store(h1, &out[((size_t)s * BATCH + bB) * HDIM + j]);
        }
        // no bottom barrier: next top's yG*/xh* writes WAR-safe (gap spans
        // B2+B3); yh*/uh* gaps span B3+B1 / B1+B2. WSL ring is wave-private:
        // buffer d reused only 3 chunks later, after its ds_reads completed
        // (same-wave lgkmcnt ordering) -- no cross-wave hazard.
    }
}

extern "C" void kernel_launch(void* const* d_in, const int* in_sizes, int n_in,
                              void* d_out, int out_size, void* d_ws, size_t ws_size,
                              hipStream_t stream) {
    const float* x    = (const float*)d_in[0];
    const float* tvec = (const float*)d_in[1];
    const float* W_ih = (const float*)d_in[2];
    const float* W_hh = (const float*)d_in[3];
    const float* b_ih = (const float*)d_in[4];
    const float* b_hh = (const float*)d_in[5];
    const float* W1   = (const float*)d_in[6];
    const float* b1   = (const float*)d_in[7];
    const float* W2   = (const float*)d_in[8];
    const float* b2   = (const float*)d_in[9];
    float* out = (float*)d_out;

    h8* WS = (h8*)d_ws;   // 60 * 512 * 16 B = 491520 B

    hipLaunchKernelGGL(prep_kernel, dim3(120), dim3(256), 0, stream,
                       W_ih, W_hh, WS);
    hipLaunchKernelGGL(odegru_kernel, dim3(BATCH / 2), dim3(512), 0, stream,
                       x, tvec, b_ih, b_hh, W1, b1, W2, b2, WS, out);
}

// Round 21
// 1195.005 us; speedup vs baseline: 1.5610x; 1.3943x over previous
//
#include <hip/hip_runtime.h>

// ODE-GRU on MI355X, round 21 — restore round-16 champion (1200 us).
// 256 blocks x 512 thr, dual-row register-amortized f16 dot2, DPP
// reductions, forward Euler, 3 barriers/step, nontemporal out.
// Four structural variants lost to this (r17 thread-split: instruction
// bloat; r18 LDS weights: neutral-negative; r19 MFMA: 32-CU cap; r20
// async DMA: LDS round-trip + vmcnt serialization). Constraint set is
// closed: 1 weight stream/CU -> 1 block/CU -> 8 waves/CU TLP cap;
// >~100 live VGPR demotes; Euler = drift minimum; 3 barriers = floor.

#define SEQ   256
#define BATCH 512
#define DIN   54
#define HDIM  256
#define DH    64

typedef _Float16 h2 __attribute__((ext_vector_type(2)));
typedef _Float16 h8 __attribute__((ext_vector_type(8)));

#define PX(v, p) __builtin_shufflevector((v), (v), 2*(p), 2*(p)+1)

#if defined(__has_builtin)
#  if __has_builtin(__builtin_amdgcn_fdot2)
#    define FDOT2(a, b, c) __builtin_amdgcn_fdot2((a), (b), (c), false)
#  endif
#endif
#ifndef FDOT2
#  define FDOT2(a, b, c) fmaf((float)(a)[0], (float)(b)[0], \
                         fmaf((float)(a)[1], (float)(b)[1], (c)))
#endif

__device__ __forceinline__ float rcp_f(float x) { return __builtin_amdgcn_rcpf(x); }

__device__ __forceinline__ float fast_tanh(float x) {
    x = fminf(15.0f, fmaxf(-15.0f, x));
    float e = __expf(2.0f * x);
    return 1.0f - 2.0f * rcp_f(e + 1.0f);
}
__device__ __forceinline__ float fast_sigmoid(float x) {
    x = fminf(30.0f, fmaxf(-30.0f, x));
    return rcp_f(1.0f + __expf(-x));
}

// x + dpp_permute(x): cross-lane add at VALU latency.
// 0xB1 quad_perm lane^1; 0x4E quad_perm lane^2; 0x141 row_half_mirror
// (8-lane finisher once quad-uniform). Validated r9/r12/r13/r16.
template <int CTRL>
__device__ __forceinline__ float dppadd(float x) {
    return x + __int_as_float(
        __builtin_amdgcn_mov_dpp(__float_as_int(x), CTRL, 0xF, 0xF, true));
}

// 4 dot2: accumulate h8 W . h8 Y into A
#define DOT8(A, W, Y) { \
    A = FDOT2(PX(W,0), PX(Y,0), A); A = FDOT2(PX(W,1), PX(Y,1), A); \
    A = FDOT2(PX(W,2), PX(Y,2), A); A = FDOT2(PX(W,3), PX(Y,3), A); }

// ---- prep: f16 GRU weights in [chunk][thread] coalesced layout ----
// WHx: 24576 h8. id = g*8192 + q*512 + t ; holds W_hh[j+256g][p*128+q*8 ..+8]
// WIx:  6144 h8. id = g*2048 + q*512 + t ; holds W_ih[j+256g][p*32+q*8 ..+8]
//                (cols >= 54 zero-padded), j=t>>1, p=t&1.
__global__ __launch_bounds__(256)
void prep_kernel(const float* __restrict__ W_ih, const float* __restrict__ W_hh,
                 h8* __restrict__ WHx, h8* __restrict__ WIx)
{
    const int id = blockIdx.x * 256 + threadIdx.x;
    if (id < 24576) {
        const int g = id >> 13, rem = id & 8191;
        const int q = rem >> 9, t = rem & 511;
        const int j = t >> 1, p = t & 1;
        const float* src = W_hh + (size_t)(j + 256 * g) * HDIM + p * 128 + q * 8;
        h8 v;
        #pragma unroll
        for (int e = 0; e < 8; ++e) v[e] = (_Float16)src[e];
        WHx[id] = v;
    } else if (id < 24576 + 6144) {
        const int id2 = id - 24576;
        const int g = id2 >> 11, rem = id2 & 2047;
        const int q = rem >> 9, t = rem & 511;
        const int j = t >> 1, p = t & 1;
        h8 v;
        #pragma unroll
        for (int e = 0; e < 8; ++e) {
            const int col = p * 32 + q * 8 + e;
            v[e] = (col < DIN) ? (_Float16)W_ih[(size_t)(j + 256 * g) * DIN + col]
                               : (_Float16)0.0f;
        }
        WIx[id2] = v;
    }
}

__global__ void
__attribute__((amdgpu_flat_work_group_size(512, 512), amdgpu_waves_per_eu(2, 2)))
odegru_kernel(const float* __restrict__ x,
              const float* __restrict__ tvec,
              const float* __restrict__ b_ih,
              const float* __restrict__ b_hh,
              const float* __restrict__ W1,
              const float* __restrict__ b1,
              const float* __restrict__ W2,
              const float* __restrict__ b2,
              const h8* __restrict__ WHx,
              const h8* __restrict__ WIx,
              float* __restrict__ out)
{
    const int t  = threadIdx.x;          // 0..511
    const int b0 = blockIdx.x * 2;       // batch row A
    const int bB = b0 + 1;               // batch row B
    const int j  = t >> 1;               // element 0..255
    const int p  = t & 1;                // pair half
    const int i1 = t >> 3;               // drift stage1 output 0..63
    const int k8 = t & 7;                // stage1 k-chunk

    __shared__ __align__(16) _Float16 yG0[HDIM], yG1[HDIM];   // GRU-input y
    __shared__ __align__(16) _Float16 yh0[HDIM], yh1[HDIM];   // drift y
    __shared__ __align__(16) _Float16 uh0[DH],  uh1[DH];
    __shared__ __align__(16) _Float16 xh0[64],  xh1[64];

    // Drift weights -> 8 named h8 vars (32 VGPRs), shared by both rows.
    h8 w1m0, w1m1, w1m2, w1m3, w2q0, w2q1, w2q2, w2q3;
    {
        const float* base = W1 + (size_t)i1 * HDIM + k8 * 8;
        h8 v;
        #pragma unroll
        for (int e = 0; e < 8; ++e) v[e] = (_Float16)base[e +   0]; w1m0 = v;
        #pragma unroll
        for (int e = 0; e < 8; ++e) v[e] = (_Float16)base[e +  64]; w1m1 = v;
        #pragma unroll
        for (int e = 0; e < 8; ++e) v[e] = (_Float16)base[e + 128]; w1m2 = v;
        #pragma unroll
        for (int e = 0; e < 8; ++e) v[e] = (_Float16)base[e + 192]; w1m3 = v;
    }
    {
        const float* base = W2 + (size_t)j * DH + p * 32;
        h8 v;
        #pragma unroll
        for (int e = 0; e < 8; ++e) v[e] = (_Float16)base[e +  0]; w2q0 = v;
        #pragma unroll
        for (int e = 0; e < 8; ++e) v[e] = (_Float16)base[e +  8]; w2q1 = v;
        #pragma unroll
        for (int e = 0; e < 8; ++e) v[e] = (_Float16)base[e + 16]; w2q2 = v;
        #pragma unroll
        for (int e = 0; e < 8; ++e) v[e] = (_Float16)base[e + 24]; w2q3 = v;
    }

    const float b1r  = b1[i1];
    const float b2r  = b2[j];
    const float bihr = b_ih[j], bihz = b_ih[j + HDIM], bihn = b_ih[j + 2 * HDIM];
    const float bhhr = b_hh[j], bhhz = b_hh[j + HDIM], bhhn = b_hh[j + 2 * HDIM];

    float h0 = 0.0f, h1 = 0.0f;

    for (int i = 0; i < SEQ; ++i) {
        const int s = SEQ - 1 - i;

        if (t < 64) {
            xh0[t] = (t < DIN) ? (_Float16)x[((size_t)s * BATCH + b0) * DIN + t]
                               : (_Float16)0.0f;
        } else if (t < 128) {
            const int u = t - 64;
            xh1[u] = (u < DIN) ? (_Float16)x[((size_t)s * BATCH + bB) * DIN + u]
                               : (_Float16)0.0f;
        }
        if (p == 0) { yG0[j] = (_Float16)h0; yG1[j] = (_Float16)h1; }
        __syncthreads();                                   // B1 (top)

        // ---- GRU: each weight load feeds BOTH rows (r13 structure) ----
        float xr0 = 0.f, xz0 = 0.f, xn0 = 0.f;
        float xr1 = 0.f, xz1 = 0.f, xn1 = 0.f;
        #pragma unroll
        for (int q = 0; q < 4; ++q) {
            h8 wr = WIx[(0 * 4 + q) * 512 + t];
            h8 wz = WIx[(1 * 4 + q) * 512 + t];
            h8 wn = WIx[(2 * 4 + q) * 512 + t];
            h8 xv0 = *(const h8*)(xh0 + p * 32 + q * 8);
            h8 xv1 = *(const h8*)(xh1 + p * 32 + q * 8);
            DOT8(xr0, wr, xv0) DOT8(xr1, wr, xv1)
            DOT8(xz0, wz, xv0) DOT8(xz1, wz, xv1)
            DOT8(xn0, wn, xv0) DOT8(xn1, wn, xv1)
        }
        float hr0 = 0.f, hz0 = 0.f, hn0 = 0.f;
        float hr1 = 0.f, hz1 = 0.f, hn1 = 0.f;
        #pragma unroll 2
        for (int q = 0; q < 16; ++q) {
            h8 wr = WHx[(0 * 16 + q) * 512 + t];
            h8 wz = WHx[(1 * 16 + q) * 512 + t];
            h8 wn = WHx[(2 * 16 + q) * 512 + t];
            h8 yv0 = *(const h8*)(yG0 + p * 128 + q * 8);
            h8 yv1 = *(const h8*)(yG1 + p * 128 + q * 8);
            DOT8(hr0, wr, yv0) DOT8(hr1, wr, yv1)
            DOT8(hz0, wz, yv0) DOT8(hz1, wz, yv1)
            DOT8(hn0, wn, yv0) DOT8(hn1, wn, yv1)
        }
        {
            float Rp = dppadd<0xB1>(xr0 + hr0);
            float Zp = dppadd<0xB1>(xz0 + hz0);
            float Ip = dppadd<0xB1>(xn0);
            float Hp = dppadd<0xB1>(hn0);
            float r_g = fast_sigmoid(Rp + bihr + bhhr);
            float z_g = fast_sigmoid(Zp + bihz + bhhz);
            float n_g = fast_tanh(Ip + bihn + r_g * (Hp + bhhn));
            h0 = n_g + z_g * (h0 - n_g);
        }
        {
            float Rp = dppadd<0xB1>(xr1 + hr1);
            float Zp = dppadd<0xB1>(xz1 + hz1);
            float Ip = dppadd<0xB1>(xn1);
            float Hp = dppadd<0xB1>(hn1);
            float r_g = fast_sigmoid(Rp + bihr + bhhr);
            float z_g = fast_sigmoid(Zp + bihz + bhhz);
            float n_g = fast_tanh(Ip + bihn + r_g * (Hp + bhhn));
            h1 = n_g + z_g * (h1 - n_g);
        }
        // no barrier: drift writes yh* (not yG*); yG* WAR gap spans B2+B3.

        // ---- ODE integrate: forward Euler (1 dual-row drift) ----
        const float t0v = tvec[s];
        const float t1v = (s > 0) ? tvec[s - 1] : tvec[0];
        const float dt  = (t1v - t0v);

        if (dt != 0.0f) {   // block-uniform; dt==0 only at s==0 (exact skip)
            if (p == 0) { yh0[j] = (_Float16)h0; yh1[j] = (_Float16)h1; }
            __syncthreads();                               // B2
            float a00 = 0.f, a01 = 0.f, a10 = 0.f, a11 = 0.f;
            {
                h8 v;
                v = *(const h8*)(yh0 + k8 * 8 +   0); DOT8(a00, w1m0, v)
                v = *(const h8*)(yh0 + k8 * 8 +  64); DOT8(a01, w1m1, v)
                v = *(const h8*)(yh0 + k8 * 8 + 128); DOT8(a00, w1m2, v)
                v = *(const h8*)(yh0 + k8 * 8 + 192); DOT8(a01, w1m3, v)
                v = *(const h8*)(yh1 + k8 * 8 +   0); DOT8(a10, w1m0, v)
                v = *(const h8*)(yh1 + k8 * 8 +  64); DOT8(a11, w1m1, v)
                v = *(const h8*)(yh1 + k8 * 8 + 128); DOT8(a10, w1m2, v)
                v = *(const h8*)(yh1 + k8 * 8 + 192); DOT8(a11, w1m3, v)
            }
            float as0 = a00 + a01, as1 = a10 + a11;
            as0 = dppadd<0xB1>(as0);  as1 = dppadd<0xB1>(as1);
            as0 = dppadd<0x4E>(as0);  as1 = dppadd<0x4E>(as1);
            as0 = dppadd<0x141>(as0); as1 = dppadd<0x141>(as1);
            float uu0 = fast_tanh(as0 + b1r);
            float uu1 = fast_tanh(as1 + b1r);
            if (k8 == 0) { uh0[i1] = (_Float16)uu0; uh1[i1] = (_Float16)uu1; }
            __syncthreads();                               // B3
            float c00 = 0.f, c01 = 0.f, c10 = 0.f, c11 = 0.f;
            {
                h8 u;
                u = *(const h8*)(uh0 + p * 32 +  0); DOT8(c00, w2q0, u)
                u = *(const h8*)(uh0 + p * 32 +  8); DOT8(c01, w2q1, u)
                u = *(const h8*)(uh0 + p * 32 + 16); DOT8(c00, w2q2, u)
                u = *(const h8*)(uh0 + p * 32 + 24); DOT8(c01, w2q3, u)
                u = *(const h8*)(uh1 + p * 32 +  0); DOT8(c10, w2q0, u)
                u = *(const h8*)(uh1 + p * 32 +  8); DOT8(c11, w2q1, u)
                u = *(const h8*)(uh1 + p * 32 + 16); DOT8(c10, w2q2, u)
                u = *(const h8*)(uh1 + p * 32 + 24); DOT8(c11, w2q3, u)
            }
            float k0 = dppadd<0xB1>(c00 + c01) + b2r;
            float k1 = dppadd<0xB1>(c10 + c11) + b2r;
            h0 = fmaf(dt, k0, h0);
            h1 = fmaf(dt, k1, h1);
        } else {
            __syncthreads();   // degenerate dt: keep next-step writes ordered
        }

        if (p == 0) {
            __builtin_nontemporal_store(h0, &out[((size_t)s * BATCH + b0) * HDIM + j]);
            __builtin_nontemporal_store(h1, &out[((size_t)s * BATCH + bB) * HDIM + j]);
        }
        // no bottom barrier: next top's yG*/xh* writes WAR-safe (gap spans
        // B2+B3 of this step); yh*/uh* gaps span B3+B1 / B1+B2 respectively.
    }
}

extern "C" void kernel_launch(void* const* d_in, const int* in_sizes, int n_in,
                              void* d_out, int out_size, void* d_ws, size_t ws_size,
                              hipStream_t stream) {
    const float* x    = (const float*)d_in[0];
    const float* tvec = (const float*)d_in[1];
    const float* W_ih = (const float*)d_in[2];
    const float* W_hh = (const float*)d_in[3];
    const float* b_ih = (const float*)d_in[4];
    const float* b_hh = (const float*)d_in[5];
    const float* W1   = (const float*)d_in[6];
    const float* b1   = (const float*)d_in[7];
    const float* W2   = (const float*)d_in[8];
    const float* b2   = (const float*)d_in[9];
    float* out = (float*)d_out;

    h8* WHx = (h8*)d_ws;                                   // 24576*16 = 393216 B
    h8* WIx = (h8*)((char*)d_ws + 24576 * 16);             //  6144*16 =  98304 B

    hipLaunchKernelGGL(prep_kernel, dim3(120), dim3(256), 0, stream,
                       W_ih, W_hh, WHx, WIx);
    hipLaunchKernelGGL(odegru_kernel, dim3(BATCH / 2), dim3(512), 0, stream,
                       x, tvec, b_ih, b_hh, W1, b1, W2, b2, WHx, WIx, out);
}